// Round 11
// baseline (1054.347 us; speedup 1.0000x reference)
//
#include <hip/hip_runtime.h>
#include <math.h>

#define NB 128
#define NKK 64
#define ND 1536
#define NEM 512
#define NH 1024
#define NVOC 10000
#define NT 30
#define CHT 6

#define BM 128
#define BN 64
#define BK 64

typedef __bf16 bf16x8 __attribute__((ext_vector_type(8)));
typedef __bf16 bf16x4 __attribute__((ext_vector_type(4)));
typedef float f32x4 __attribute__((ext_vector_type(4)));

__device__ __forceinline__ float ftanh(float x) {
    float e = __expf(2.f * x);
    return 1.f - 2.f * __builtin_amdgcn_rcpf(e + 1.f);
}
__device__ __forceinline__ float fsig(float x) {
    return __builtin_amdgcn_rcpf(1.f + __expf(-x));
}

// ---------------- sort + target/lens + widx + live-row map ----------------
__global__ void sort_kernel(const int* __restrict__ cap, const int* __restrict__ w,
                            float* __restrict__ out_target, float* __restrict__ out_lens,
                            int* __restrict__ order, int* __restrict__ lens_s,
                            int* __restrict__ widx, int* __restrict__ live_tb,
                            int* __restrict__ row_of, int* __restrict__ counts) {
    __shared__ int lcap[NB];
    __shared__ int sord[NB];
    __shared__ int slen[NB];
    int b = threadIdx.x;
    lcap[b] = cap[b];
    __syncthreads();
    int lb = lcap[b];
    int pos = 0;
    for (int j = 0; j < NB; j++) {
        int lj = lcap[j];
        if (lj > lb || (lj == lb && j < b)) pos++;
    }
    sord[pos] = b;
    __syncthreads();
    int src = sord[b];
    order[b] = src;
    int ln = lcap[src] - 1;
    lens_s[b] = ln;
    slen[b] = ln;
    out_lens[b] = (float)ln;
    for (int j = 0; j < NT; j++)
        out_target[b * NT + j] = (float)w[src * (NT + 1) + j + 1];
    for (int t = 0; t < NT; t++)
        widx[t * NB + b] = w[src * (NT + 1) + t];
    __syncthreads();
    // b-major compaction: rows for batch b are [prefix[b], prefix[b]+ln)
    int prefix = 0;
    for (int j = 0; j < b; j++) prefix += slen[j];
    for (int t = 0; t < ln; t++) {
        row_of[t * NB + b] = prefix + t;
        live_tb[prefix + t] = t * NB + b;
    }
    if (b == NB - 1) {
        int nLive = prefix + ln;
        counts[0] = nLive;
        counts[1] = (nLive + BM - 1) & ~(BM - 1);
    }
}

// ---------------- init c + 4 ghh partials ----------------
__global__ void init_kernel(float* __restrict__ c, float* __restrict__ g0,
                            float* __restrict__ g1, float* __restrict__ g2,
                            float* __restrict__ g3) {
    int tid = blockIdx.x * 256 + threadIdx.x;
    if (tid < NB * NH) c[tid] = 0.f;
    if (tid < NB * 5120) { g0[tid] = 0.f; g1[tid] = 0.f; g2[tid] = 0.f; g3[tid] = 0.f; }
}

// ---------------- mean over K (sorted order), bf16 out ----------------
__global__ void meanim_kernel(const float* __restrict__ im, const int* __restrict__ order,
                              __bf16* __restrict__ meanb) {
    int b = blockIdx.x;
    int src = order[b];
    const float* base = im + (size_t)src * NKK * ND;
    for (int d = threadIdx.x; d < ND; d += 256) {
        float acc = 0.f;
        for (int k = 0; k < NKK; k++) acc += base[(size_t)k * ND + d];
        meanb[b * ND + d] = (__bf16)(acc * (1.0f / NKK));
    }
}

// ---------------- permuted f32 -> bf16 of im ----------------
__global__ void conv_perm_kernel(const float* __restrict__ im, const int* __restrict__ order,
                                 __bf16* __restrict__ imb) {
    int e8 = blockIdx.x * 256 + threadIdx.x;
    size_t elem = (size_t)e8 * 8;
    int bp = (int)(elem / (NKK * ND));
    size_t rem = elem % (NKK * ND);
    const float* src = im + (size_t)order[bp] * NKK * ND + rem;
    float4 f0 = *(const float4*)(src);
    float4 f1 = *(const float4*)(src + 4);
    bf16x8 v = {(__bf16)f0.x, (__bf16)f0.y, (__bf16)f0.z, (__bf16)f0.w,
                (__bf16)f1.x, (__bf16)f1.y, (__bf16)f1.z, (__bf16)f1.w};
    *(bf16x8*)(imb + elem) = v;
}

// ---------------- LDS-tiled transpose + f32->bf16 pack ----------------
__global__ __launch_bounds__(256) void transpose_pack(
    const float* __restrict__ src, int ldn, int K, int N,
    __bf16* __restrict__ dst, int ldk) {
    __shared__ float tile[64][65];
    int k0 = blockIdx.y * 64, n0 = blockIdx.x * 64;
    int t = threadIdx.x;
    int kr = t >> 2, nc0 = (t & 3) * 16;
    int kk = k0 + kr;
#pragma unroll
    for (int j = 0; j < 16; j += 4) {
        int nn = n0 + nc0 + j;
        float4 v = make_float4(0.f, 0.f, 0.f, 0.f);
        if (kk < K && nn + 3 < N) v = *(const float4*)(src + (size_t)kk * ldn + nn);
        else if (kk < K) {
            float tmp[4] = {0.f, 0.f, 0.f, 0.f};
            for (int q = 0; q < 4; q++) if (nn + q < N) tmp[q] = src[(size_t)kk * ldn + nn + q];
            v = make_float4(tmp[0], tmp[1], tmp[2], tmp[3]);
        }
        tile[kr][nc0 + j + 0] = v.x; tile[kr][nc0 + j + 1] = v.y;
        tile[kr][nc0 + j + 2] = v.z; tile[kr][nc0 + j + 3] = v.w;
    }
    __syncthreads();
    int nr = t >> 2, kc0 = (t & 3) * 16;
    if (n0 + nr < N) {
        __bf16* drow = dst + (size_t)(n0 + nr) * ldk + k0 + kc0;
#pragma unroll
        for (int j = 0; j < 16; j++)
            if (k0 + kc0 + j < K) drow[j] = (__bf16)tile[kc0 + j][nr];
    }
}

// ---------------- f32 -> bf16 vector convert ----------------
__global__ void conv_bf16_vec(const float* __restrict__ src, __bf16* __restrict__ dst, int n4) {
    int id = blockIdx.x * 256 + threadIdx.x;
    if (id < n4) {
        float4 v = *(const float4*)(src + (size_t)id * 4);
        __bf16* d = dst + (size_t)id * 4;
        d[0] = (__bf16)v.x; d[1] = (__bf16)v.y; d[2] = (__bf16)v.z; d[3] = (__bf16)v.w;
    }
}

// ---------------- bias packs ----------------
__global__ void pack_biases(const float* __restrict__ b_ih, const float* __restrict__ b_hh,
                            const float* __restrict__ b_xg, const float* __restrict__ b_hg,
                            const float* __restrict__ bh, const float* __restrict__ bs,
                            float* __restrict__ bstep, float* __restrict__ b2) {
    int i = blockIdx.x * 256 + threadIdx.x;
    if (i < 4096) bstep[i] = b_ih[i] + b_hh[i];
    else bstep[i] = b_xg[i - 4096] + b_hg[i - 4096];
    if (i < 1024) b2[i] = bh[i];
    else if (i < 2048) b2[i] = bs[i - 1024];
}

// =======================================================================
// gemm_k: MFMA GEMM (proven R3 core), z-batch strides.
// AMODE 0: bf16 A direct. AMODE 1: x-concat [emb(widx[r]) | g(r&127)].
// AMODE 2: bf16 A with live-row gather (live_tb/cnts); early-exit past pad.
// swz: 0 none; 1 m-panel-grouped (gridY%8==0); 3 contiguous-chunk bijective.
// =======================================================================
template <int AMODE, bool RELU, bool OUTBF>
__global__ __launch_bounds__(256) void gemm_k(
    const void* __restrict__ Aptr, int lda,
    const __bf16* __restrict__ Bt, int ldb,
    const float* __restrict__ bias,
    void* __restrict__ Cptr, int ldc,
    int N, int K,
    const int* __restrict__ widx,
    const __bf16* __restrict__ embb, const __bf16* __restrict__ gbf,
    int swz, size_t sA, size_t sB, size_t sBias, size_t sC,
    const int* __restrict__ live_tb, const int* __restrict__ cnts) {
    const int t = threadIdx.x;
    const int lane = t & 63;
    const int wid = t >> 6;
    const int wr = wid >> 1, wc = wid & 1;
    int bx = blockIdx.x, by = blockIdx.y;
    if (swz == 1) {
        int L = by * gridDim.x + bx;
        int xcd = L & 7, q = L >> 3;
        by = xcd * (gridDim.y >> 3) + q / gridDim.x;
        bx = q % gridDim.x;
    } else if (swz == 3) {
        int total = gridDim.x * gridDim.y;
        int L = by * gridDim.x + bx;
        int xcd = L & 7, idx = L >> 3;
        int newL = xcd * (total >> 3) + idx;
        by = newL / gridDim.x;
        bx = newL % gridDim.x;
    }
    const int z = blockIdx.z;
    const int m0 = by * BM;
    const int n0 = bx * BN;
    if (AMODE == 2 && m0 >= cnts[1]) return;
    const int lr = lane & 15, lg = lane >> 4, lr8 = lr & 7;

    __shared__ __bf16 As[BM * BK];
    __shared__ __bf16 Bs[BN * BK];

    f32x4 acc[4][2];
#pragma unroll
    for (int i = 0; i < 4; i++)
#pragma unroll
        for (int j = 0; j < 2; j++) acc[i][j] = (f32x4){0.f, 0.f, 0.f, 0.f};

    const int s_row = t >> 1;
    const int s_g0 = (t & 1) * 4;
    const int s_col = t >> 2;
    const int s_bg0 = (t & 3) * 2;
    const int r8 = s_row & 7, c8 = s_col & 7;
    const int aw0 = (s_row << 6) + (((s_g0 + 0) ^ r8) << 3);
    const int aw1 = (s_row << 6) + (((s_g0 + 1) ^ r8) << 3);
    const int aw2 = (s_row << 6) + (((s_g0 + 2) ^ r8) << 3);
    const int aw3 = (s_row << 6) + (((s_g0 + 3) ^ r8) << 3);
    const int bw0 = (s_col << 6) + (((s_bg0 + 0) ^ c8) << 3);
    const int bw1 = (s_col << 6) + (((s_bg0 + 1) ^ c8) << 3);
    const int rA0 = (wr * 64 + 0 * 16 + lr) << 6;
    const int rA1 = (wr * 64 + 1 * 16 + lr) << 6;
    const int rA2 = (wr * 64 + 2 * 16 + lr) << 6;
    const int rA3 = (wr * 64 + 3 * 16 + lr) << 6;
    const int cB0 = (wc * 32 + 0 * 16 + lr) << 6;
    const int cB1 = (wc * 32 + 1 * 16 + lr) << 6;

    const __bf16* a_srcb = nullptr;
    const __bf16* e_base = nullptr;
    const __bf16* g_base = nullptr;
    if (AMODE == 1) {
        int r = m0 + s_row;
        e_base = embb + (size_t)widx[r] * NEM + s_g0 * 8;
        g_base = gbf + (size_t)(r & 127) * NEM + s_g0 * 8 - NEM;
    } else if (AMODE == 2) {
        int r = m0 + s_row;
        int nl = cnts[0];
        int rr = r < nl ? r : nl - 1;
        a_srcb = (const __bf16*)Aptr + (size_t)live_tb[rr] * lda + s_g0 * 8;
    } else {
        a_srcb = (const __bf16*)Aptr + z * sA + (size_t)(m0 + s_row) * lda + s_g0 * 8;
    }
    const __bf16* b_src = Bt + z * sB + (size_t)(n0 + s_col) * ldb + s_bg0 * 8;
    const bool b_ok = (n0 + s_col) < N;

    auto loadA = [&](int k0, bf16x8& a0, bf16x8& a1, bf16x8& a2, bf16x8& a3) {
        if (AMODE == 1) {
            int kk = k0 + s_g0 * 8;
            const bf16x8* p = (const bf16x8*)((kk < NEM ? e_base : g_base) + k0);
            a0 = p[0]; a1 = p[1]; a2 = p[2]; a3 = p[3];
        } else {
            const bf16x8* p = (const bf16x8*)(a_srcb + k0);
            a0 = p[0]; a1 = p[1]; a2 = p[2]; a3 = p[3];
        }
    };
    auto loadB = [&](int k0, bf16x8& b0, bf16x8& b1) {
        if (b_ok) {
            const bf16x8* p = (const bf16x8*)(b_src + k0);
            b0 = p[0]; b1 = p[1];
        } else {
            bf16x8 zv = {};
            b0 = zv; b1 = zv;
        }
    };
    auto writeS = [&](bf16x8 a0, bf16x8 a1, bf16x8 a2, bf16x8 a3, bf16x8 b0, bf16x8 b1) {
        *(bf16x8*)&As[aw0] = a0; *(bf16x8*)&As[aw1] = a1;
        *(bf16x8*)&As[aw2] = a2; *(bf16x8*)&As[aw3] = a3;
        *(bf16x8*)&Bs[bw0] = b0; *(bf16x8*)&Bs[bw1] = b1;
    };
    auto compute = [&]() {
#pragma unroll
        for (int ks = 0; ks < 2; ks++) {
            const int gsw = ((ks * 4 + lg) ^ lr8) << 3;
            bf16x8 af0 = *(const bf16x8*)&As[rA0 + gsw];
            bf16x8 af1 = *(const bf16x8*)&As[rA1 + gsw];
            bf16x8 af2 = *(const bf16x8*)&As[rA2 + gsw];
            bf16x8 af3 = *(const bf16x8*)&As[rA3 + gsw];
            bf16x8 bv0 = *(const bf16x8*)&Bs[cB0 + gsw];
            bf16x8 bv1 = *(const bf16x8*)&Bs[cB1 + gsw];
            acc[0][0] = __builtin_amdgcn_mfma_f32_16x16x32_bf16(af0, bv0, acc[0][0], 0, 0, 0);
            acc[0][1] = __builtin_amdgcn_mfma_f32_16x16x32_bf16(af0, bv1, acc[0][1], 0, 0, 0);
            acc[1][0] = __builtin_amdgcn_mfma_f32_16x16x32_bf16(af1, bv0, acc[1][0], 0, 0, 0);
            acc[1][1] = __builtin_amdgcn_mfma_f32_16x16x32_bf16(af1, bv1, acc[1][1], 0, 0, 0);
            acc[2][0] = __builtin_amdgcn_mfma_f32_16x16x32_bf16(af2, bv0, acc[2][0], 0, 0, 0);
            acc[2][1] = __builtin_amdgcn_mfma_f32_16x16x32_bf16(af2, bv1, acc[2][1], 0, 0, 0);
            acc[3][0] = __builtin_amdgcn_mfma_f32_16x16x32_bf16(af3, bv0, acc[3][0], 0, 0, 0);
            acc[3][1] = __builtin_amdgcn_mfma_f32_16x16x32_bf16(af3, bv1, acc[3][1], 0, 0, 0);
        }
    };

    bf16x8 a0, a1, a2, a3, b0, b1;
    bf16x8 c0, c1, c2, c3, d0, d1;
    loadA(0, a0, a1, a2, a3);
    loadB(0, b0, b1);
    for (int k0 = 0; k0 < K; k0 += 2 * BK) {
        writeS(a0, a1, a2, a3, b0, b1);
        __syncthreads();
        loadA(k0 + BK, c0, c1, c2, c3);
        loadB(k0 + BK, d0, d1);
        compute();
        __syncthreads();
        writeS(c0, c1, c2, c3, d0, d1);
        __syncthreads();
        if (k0 + 2 * BK < K) {
            loadA(k0 + 2 * BK, a0, a1, a2, a3);
            loadB(k0 + 2 * BK, b0, b1);
        }
        compute();
        __syncthreads();
    }

    const float* bias_z = bias + z * sBias;
    float* Cf = (float*)Cptr + z * sC;
    __bf16* Cb = (__bf16*)Cptr + z * sC;
#pragma unroll
    for (int mi = 0; mi < 4; mi++) {
#pragma unroll
        for (int ni = 0; ni < 2; ni++) {
            int col = n0 + wc * 32 + ni * 16 + lr;
            if (col < N) {
                float bb = bias_z[col];
#pragma unroll
                for (int rr = 0; rr < 4; rr++) {
                    int row = m0 + wr * 64 + mi * 16 + lg * 4 + rr;
                    float v = acc[mi][ni][rr] + bb;
                    if (RELU) v = fmaxf(v, 0.f);
                    if (OUTBF) Cb[(size_t)row * ldc + col] = (__bf16)v;
                    else Cf[(size_t)row * ldc + col] = v;
                }
            }
        }
    }
}

// =======================================================================
// step_gemm: device core (M=128, bf16 A, f32 out, nullable bias)
// =======================================================================
__device__ __forceinline__ void step_gemm(
    __bf16* As, __bf16* Bs,
    const __bf16* __restrict__ Ab, int lda,
    const __bf16* __restrict__ Bt, int ldb,
    const float* __restrict__ bias,
    float* __restrict__ C, int ldc, int N, int n0, int K) {
    const int t = threadIdx.x;
    const int lane = t & 63;
    const int wid = t >> 6;
    const int wr = wid >> 1, wc = wid & 1;
    const int lr = lane & 15, lg = lane >> 4, lr8 = lr & 7;

    f32x4 acc[4][2];
#pragma unroll
    for (int i = 0; i < 4; i++)
#pragma unroll
        for (int j = 0; j < 2; j++) acc[i][j] = (f32x4){0.f, 0.f, 0.f, 0.f};

    const int s_row = t >> 1;
    const int s_g0 = (t & 1) * 4;
    const int s_col = t >> 2;
    const int s_bg0 = (t & 3) * 2;
    const int r8 = s_row & 7, c8 = s_col & 7;
    const int aw0 = (s_row << 6) + (((s_g0 + 0) ^ r8) << 3);
    const int aw1 = (s_row << 6) + (((s_g0 + 1) ^ r8) << 3);
    const int aw2 = (s_row << 6) + (((s_g0 + 2) ^ r8) << 3);
    const int aw3 = (s_row << 6) + (((s_g0 + 3) ^ r8) << 3);
    const int bw0 = (s_col << 6) + (((s_bg0 + 0) ^ c8) << 3);
    const int bw1 = (s_col << 6) + (((s_bg0 + 1) ^ c8) << 3);
    const int rA0 = (wr * 64 + 0 * 16 + lr) << 6;
    const int rA1 = (wr * 64 + 1 * 16 + lr) << 6;
    const int rA2 = (wr * 64 + 2 * 16 + lr) << 6;
    const int rA3 = (wr * 64 + 3 * 16 + lr) << 6;
    const int cB0 = (wc * 32 + 0 * 16 + lr) << 6;
    const int cB1 = (wc * 32 + 1 * 16 + lr) << 6;

    const __bf16* a_src = Ab + (size_t)s_row * lda + s_g0 * 8;
    const __bf16* b_src = Bt + (size_t)(n0 + s_col) * ldb + s_bg0 * 8;
    const bool b_ok = (n0 + s_col) < N;

    auto loadA = [&](int k0, bf16x8& a0, bf16x8& a1, bf16x8& a2, bf16x8& a3) {
        const bf16x8* p = (const bf16x8*)(a_src + k0);
        a0 = p[0]; a1 = p[1]; a2 = p[2]; a3 = p[3];
    };
    auto loadB = [&](int k0, bf16x8& b0, bf16x8& b1) {
        if (b_ok) {
            const bf16x8* p = (const bf16x8*)(b_src + k0);
            b0 = p[0]; b1 = p[1];
        } else {
            bf16x8 zv = {};
            b0 = zv; b1 = zv;
        }
    };
    auto writeS = [&](bf16x8 a0, bf16x8 a1, bf16x8 a2, bf16x8 a3, bf16x8 b0, bf16x8 b1) {
        *(bf16x8*)&As[aw0] = a0; *(bf16x8*)&As[aw1] = a1;
        *(bf16x8*)&As[aw2] = a2; *(bf16x8*)&As[aw3] = a3;
        *(bf16x8*)&Bs[bw0] = b0; *(bf16x8*)&Bs[bw1] = b1;
    };
    auto compute = [&]() {
#pragma unroll
        for (int ks = 0; ks < 2; ks++) {
            const int gsw = ((ks * 4 + lg) ^ lr8) << 3;
            bf16x8 af0 = *(const bf16x8*)&As[rA0 + gsw];
            bf16x8 af1 = *(const bf16x8*)&As[rA1 + gsw];
            bf16x8 af2 = *(const bf16x8*)&As[rA2 + gsw];
            bf16x8 af3 = *(const bf16x8*)&As[rA3 + gsw];
            bf16x8 bv0 = *(const bf16x8*)&Bs[cB0 + gsw];
            bf16x8 bv1 = *(const bf16x8*)&Bs[cB1 + gsw];
            acc[0][0] = __builtin_amdgcn_mfma_f32_16x16x32_bf16(af0, bv0, acc[0][0], 0, 0, 0);
            acc[0][1] = __builtin_amdgcn_mfma_f32_16x16x32_bf16(af0, bv1, acc[0][1], 0, 0, 0);
            acc[1][0] = __builtin_amdgcn_mfma_f32_16x16x32_bf16(af1, bv0, acc[1][0], 0, 0, 0);
            acc[1][1] = __builtin_amdgcn_mfma_f32_16x16x32_bf16(af1, bv1, acc[1][1], 0, 0, 0);
            acc[2][0] = __builtin_amdgcn_mfma_f32_16x16x32_bf16(af2, bv0, acc[2][0], 0, 0, 0);
            acc[2][1] = __builtin_amdgcn_mfma_f32_16x16x32_bf16(af2, bv1, acc[2][1], 0, 0, 0);
            acc[3][0] = __builtin_amdgcn_mfma_f32_16x16x32_bf16(af3, bv0, acc[3][0], 0, 0, 0);
            acc[3][1] = __builtin_amdgcn_mfma_f32_16x16x32_bf16(af3, bv1, acc[3][1], 0, 0, 0);
        }
    };

    bf16x8 a0, a1, a2, a3, b0, b1;
    bf16x8 c0, c1, c2, c3, d0, d1;
    loadA(0, a0, a1, a2, a3);
    loadB(0, b0, b1);
    for (int k0 = 0; k0 < K; k0 += 2 * BK) {
        writeS(a0, a1, a2, a3, b0, b1);
        __syncthreads();
        loadA(k0 + BK, c0, c1, c2, c3);
        loadB(k0 + BK, d0, d1);
        compute();
        __syncthreads();
        writeS(c0, c1, c2, c3, d0, d1);
        __syncthreads();
        if (k0 + 2 * BK < K) {
            loadA(k0 + 2 * BK, a0, a1, a2, a3);
            loadB(k0 + 2 * BK, b0, b1);
        }
        compute();
        __syncthreads();
    }

#pragma unroll
    for (int mi = 0; mi < 4; mi++) {
#pragma unroll
        for (int ni = 0; ni < 2; ni++) {
            int col = n0 + wc * 32 + ni * 16 + lr;
            if (col < N) {
                float bb = bias ? bias[col] : 0.f;
#pragma unroll
                for (int rr = 0; rr < 4; rr++) {
                    int row = wr * 64 + mi * 16 + lg * 4 + rr;
                    C[(size_t)row * ldc + col] = acc[mi][ni][rr] + bb;
                }
            }
        }
    }
}

// =======================================================================
// lstm: per-step pointwise; sums 4 ghh partials
// =======================================================================
__global__ __launch_bounds__(256) void lstm_kernel(
    const __bf16* __restrict__ Xpre, const float* __restrict__ g0,
    const float* __restrict__ g1, const float* __restrict__ g2,
    const float* __restrict__ g3, float* __restrict__ c,
    __bf16* __restrict__ H_all, __bf16* __restrict__ S_all, int t) {
    int i4 = (blockIdx.x * 256 + threadIdx.x) * 4;
    int b = i4 >> 10, j = i4 & 1023;
    const __bf16* xp = Xpre + ((size_t)t * NB + b) * 5120 + j;
    size_t gof = (size_t)b * 5120 + j;
    float4 cv = *(const float4*)(c + i4);
    float cvp[4] = {cv.x, cv.y, cv.z, cv.w};
    float pre[5][4];
#pragma unroll
    for (int q = 0; q < 5; q++) {
        bf16x4 xv = *(const bf16x4*)(xp + q * 1024);
        float4 a0 = *(const float4*)(g0 + gof + q * 1024);
        float4 a1 = *(const float4*)(g1 + gof + q * 1024);
        float4 a2 = *(const float4*)(g2 + gof + q * 1024);
        float4 a3 = *(const float4*)(g3 + gof + q * 1024);
        pre[q][0] = (float)xv[0] + a0.x + a1.x + a2.x + a3.x;
        pre[q][1] = (float)xv[1] + a0.y + a1.y + a2.y + a3.y;
        pre[q][2] = (float)xv[2] + a0.z + a1.z + a2.z + a3.z;
        pre[q][3] = (float)xv[3] + a0.w + a1.w + a2.w + a3.w;
    }
    float cn4[4];
    bf16x4 hv, sv;
#pragma unroll
    for (int e = 0; e < 4; e++) {
        float cn = fsig(pre[1][e]) * cvp[e] + fsig(pre[0][e]) * ftanh(pre[2][e]);
        float tc = ftanh(cn);
        cn4[e] = cn;
        hv[e] = (__bf16)(fsig(pre[3][e]) * tc);
        sv[e] = (__bf16)(fsig(pre[4][e]) * tc);
    }
    *(float4*)(c + i4) = make_float4(cn4[0], cn4[1], cn4[2], cn4[3]);
    *(bf16x4*)(H_all + (size_t)t * NB * NH + i4) = hv;
    *(bf16x4*)(S_all + (size_t)t * NB * NH + i4) = sv;
}

// =======================================================================
// gatesHH: ghh = h_t @ [W_hh|W_hg] (split-K 4, 320 blocks)
// =======================================================================
__global__ __launch_bounds__(256) void gatesHH_kernel(
    const __bf16* __restrict__ H_t, const __bf16* __restrict__ Whh,
    float* __restrict__ g0, float* __restrict__ g1,
    float* __restrict__ g2, float* __restrict__ g3) {
    __shared__ __bf16 As[BM * BK];
    __shared__ __bf16 Bs[BN * BK];
    int kc = blockIdx.x & 3, n = blockIdx.x >> 2;   // n 0..79
    float* outp = (kc == 0) ? g0 : (kc == 1) ? g1 : (kc == 2) ? g2 : g3;
    step_gemm(As, Bs, H_t + kc * 256, NH, Whh + kc * 256, 2048, nullptr,
              outp, 5120, 5120, n * 64, 256);
}

// =======================================================================
// attn_all: one block per (t,b); dead rows exit early
// =======================================================================
__global__ __launch_bounds__(256) void attn_all_kernel(
    const __bf16* __restrict__ VA, const __bf16* __restrict__ V,
    const __bf16* __restrict__ HPa, const __bf16* __restrict__ SWSa,
    const float* __restrict__ wa, const __bf16* __restrict__ H_all,
    const __bf16* __restrict__ S_all, __bf16* __restrict__ Z_all,
    const int* __restrict__ lens) {
    __shared__ float zscore[NKK + 1];
    __shared__ float alpha_s[NKK + 1];
    int tb = blockIdx.x;
    int b = tb & 127;
    if ((tb >> 7) >= lens[b]) return;
    int wave = threadIdx.x >> 6, lane = threadIdx.x & 63;

    float hp_reg[16], wa_reg[16];
    {
        const bf16x8* hr = (const bf16x8*)(HPa + (size_t)tb * NH + lane * 16);
        bf16x8 h0 = hr[0], h1 = hr[1];
        const float* wb = wa + lane * 16;
#pragma unroll
        for (int q = 0; q < 4; q++) {
            float4 wv = *(const float4*)(wb + q * 4);
            wa_reg[q * 4 + 0] = wv.x; wa_reg[q * 4 + 1] = wv.y;
            wa_reg[q * 4 + 2] = wv.z; wa_reg[q * 4 + 3] = wv.w;
        }
#pragma unroll
        for (int j = 0; j < 8; j++) { hp_reg[j] = (float)h0[j]; hp_reg[8 + j] = (float)h1[j]; }
    }
    for (int k = wave; k <= NKK; k += 4) {
        float p = 0.f;
        if (k < NKK) {
            const bf16x8* row = (const bf16x8*)(VA + ((size_t)(b * NKK + k)) * NH + lane * 16);
            bf16x8 v0 = row[0], v1 = row[1];
#pragma unroll
            for (int j = 0; j < 8; j++) {
                p += ftanh((float)v0[j] + hp_reg[j]) * wa_reg[j];
                p += ftanh((float)v1[j] + hp_reg[8 + j]) * wa_reg[8 + j];
            }
        } else {
            const bf16x8* sr = (const bf16x8*)(SWSa + (size_t)tb * NH + lane * 16);
            bf16x8 s0 = sr[0], s1 = sr[1];
#pragma unroll
            for (int j = 0; j < 8; j++) {
                p += ftanh((float)s0[j] + hp_reg[j]) * wa_reg[j];
                p += ftanh((float)s1[j] + hp_reg[8 + j]) * wa_reg[8 + j];
            }
        }
        for (int off = 32; off; off >>= 1) p += __shfl_down(p, off);
        if (lane == 0) zscore[k] = p;
    }
    __syncthreads();
    if (threadIdx.x == 0) {
        float mx = zscore[0];
        for (int i = 1; i <= NKK; i++) mx = fmaxf(mx, zscore[i]);
        float ssum = 0.f;
        for (int i = 0; i <= NKK; i++) { float e = __expf(zscore[i] - mx); alpha_s[i] = e; ssum += e; }
        float inv = __builtin_amdgcn_rcpf(ssum);
        for (int i = 0; i <= NKK; i++) alpha_s[i] *= inv;
    }
    __syncthreads();
    float beta = alpha_s[NKK];
    {
        int jj0 = threadIdx.x * 4;
        const __bf16* vp = V + ((size_t)b * NKK) * NH + jj0;
        float c0 = 0.f, c1 = 0.f, c2 = 0.f, c3 = 0.f;
#pragma unroll 8
        for (int k = 0; k < NKK; k++) {
            bf16x4 vv = *(const bf16x4*)(vp + (size_t)k * NH);
            float a = alpha_s[k];
            c0 += a * (float)vv[0]; c1 += a * (float)vv[1];
            c2 += a * (float)vv[2]; c3 += a * (float)vv[3];
        }
        bf16x4 s4 = *(const bf16x4*)(S_all + (size_t)tb * NH + jj0);
        bf16x4 h4 = *(const bf16x4*)(H_all + (size_t)tb * NH + jj0);
        float ob = 1.f - beta;
        bf16x4 zv;
        zv[0] = (__bf16)(beta * (float)s4[0] + ob * c0 + (float)h4[0]);
        zv[1] = (__bf16)(beta * (float)s4[1] + ob * c1 + (float)h4[1]);
        zv[2] = (__bf16)(beta * (float)s4[2] + ob * c2 + (float)h4[2]);
        zv[3] = (__bf16)(beta * (float)s4[3] + ob * c3 + (float)h4[3]);
        *(bf16x4*)(Z_all + (size_t)tb * NH + jj0) = zv;
    }
}

// =======================================================================
// softmax over vocab; COMPACT: logits row via row_of; else dense rows.
// =======================================================================
template <bool COMPACT>
__global__ __launch_bounds__(256) void softmax_kernel(
    const float* __restrict__ logitsB, const int* __restrict__ lens,
    const int* __restrict__ row_of, float* __restrict__ pred, int t0) {
    __shared__ float se[NVOC];
    __shared__ float sred[4], sred2[4];
    int r = blockIdx.x;
    int tt = r >> 7, b = r & 127;
    int t = t0 + tt;
    float* out = pred + (size_t)b * NT * NVOC + (size_t)t * NVOC;
    if (t >= lens[b]) {
        for (int v = threadIdx.x; v < NVOC; v += 256) out[v] = 0.f;
        return;
    }
    size_t srcrow = COMPACT ? (size_t)row_of[t * NB + b] : (size_t)r;
    const float* lg = logitsB + srcrow * NVOC;
    float mx = -1e30f;
    for (int v = threadIdx.x; v < NVOC; v += 256) {
        float x = lg[v];
        se[v] = x;
        mx = fmaxf(mx, x);
    }
    for (int off = 32; off; off >>= 1) mx = fmaxf(mx, __shfl_down(mx, off));
    if ((threadIdx.x & 63) == 0) sred[threadIdx.x >> 6] = mx;
    __syncthreads();
    mx = fmaxf(fmaxf(sred[0], sred[1]), fmaxf(sred[2], sred[3]));
    float ssum = 0.f;
    for (int v = threadIdx.x; v < NVOC; v += 256) {
        float e = __expf(se[v] - mx);
        se[v] = e;
        ssum += e;
    }
    for (int off = 32; off; off >>= 1) ssum += __shfl_down(ssum, off);
    if ((threadIdx.x & 63) == 0) sred2[threadIdx.x >> 6] = ssum;
    __syncthreads();
    ssum = sred2[0] + sred2[1] + sred2[2] + sred2[3];
    float inv = 1.f / ssum;
    for (int v = threadIdx.x; v < NVOC; v += 256) out[v] = se[v] * inv;
}

extern "C" void kernel_launch(void* const* d_in, const int* in_sizes, int n_in,
                              void* d_out, int out_size, void* d_ws, size_t ws_size,
                              hipStream_t stream) {
    const float* im = (const float*)d_in[0];
    const int* w_in = (const int*)d_in[1];
    const int* cap = (const int*)d_in[2];
    const float* emb = (const float*)d_in[3];
    const float* W_enc = (const float*)d_in[4];
    const float* b_enc = (const float*)d_in[5];
    const float* W_glob = (const float*)d_in[6];
    const float* b_glob = (const float*)d_in[7];
    const float* W_ih = (const float*)d_in[8];
    const float* b_ih = (const float*)d_in[9];
    const float* W_hh = (const float*)d_in[10];
    const float* b_hh = (const float*)d_in[11];
    const float* W_xg = (const float*)d_in[12];
    const float* b_xg = (const float*)d_in[13];
    const float* W_hg = (const float*)d_in[14];
    const float* b_hg = (const float*)d_in[15];
    const float* Wv = (const float*)d_in[16];
    const float* bv = (const float*)d_in[17];
    const float* Ws = (const float*)d_in[18];
    const float* bs = (const float*)d_in[19];
    const float* Wh = (const float*)d_in[20];
    const float* bh = (const float*)d_in[21];
    const float* wa = (const float*)d_in[22];
    // ba cancels in softmax(65)
    const float* W_out = (const float*)d_in[24];
    const float* b_out = (const float*)d_in[25];

    float* out = (float*)d_out;
    float* pred = out;
    float* out_target = out + (size_t)NB * NT * NVOC;
    float* out_lens = out_target + NB * NT;

    char* p = (char*)d_ws;
    size_t off = 0;
    auto carve = [&](size_t bytes) {
        void* r = p + off;
        off += (bytes + 255) & ~(size_t)255;
        return r;
    };
    int* order = (int*)carve(NB * 4);
    int* lens_s = (int*)carve(NB * 4);
    int* widx = (int*)carve(NT * NB * 4);
    int* live_tb = (int*)carve(NT * NB * 4);
    int* row_of = (int*)carve(NT * NB * 4);
    int* counts = (int*)carve(2 * 4);
    __bf16* embb = (__bf16*)carve((size_t)NVOC * NEM * 2);
    __bf16* Wstep_t = (__bf16*)carve((size_t)5120 * 2048 * 2);
    __bf16* W2t = (__bf16*)carve((size_t)2 * 1024 * 1024 * 2);
    __bf16* Wout_t = (__bf16*)carve((size_t)NVOC * 1024 * 2);
    __bf16* Wglob_t = (__bf16*)carve((size_t)512 * 1536 * 2);
    __bf16* Wenc_t = (__bf16*)carve((size_t)1024 * 1536 * 2);
    __bf16* Wv_t = (__bf16*)carve((size_t)1024 * 1024 * 2);
    float* bstep = (float*)carve(5120 * 4);
    float* b2 = (float*)carve(2048 * 4);
    __bf16* meanb = (__bf16*)carve((size_t)NB * ND * 2);
    __bf16* g_bf = (__bf16*)carve((size_t)NB * NEM * 2);
    __bf16* V_bf = (__bf16*)carve((size_t)NB * NKK * NH * 2);
    __bf16* VA_bf = (__bf16*)carve((size_t)NB * NKK * NH * 2);
    // Union region: imb (25.2 MB) -> Xpre (39.3 MB) -> logits chunk (fallback)
    void* uni = carve((size_t)NT * NB * 5120 * 2);
    __bf16* imb = (__bf16*)uni;
    __bf16* Xpre = (__bf16*)uni;
    float* logitsC = (float*)uni;
    float* ghh0 = (float*)carve((size_t)NB * 5120 * 4);
    float* ghh1 = (float*)carve((size_t)NB * 5120 * 4);
    float* ghh2 = (float*)carve((size_t)NB * 5120 * 4);
    float* ghh3 = (float*)carve((size_t)NB * 5120 * 4);
    float* c = (float*)carve((size_t)NB * NH * 4);
    __bf16* H_all = (__bf16*)carve((size_t)NT * NB * NH * 2);
    __bf16* S_all = (__bf16*)carve((size_t)NT * NB * NH * 2);
    __bf16* HPa = (__bf16*)carve((size_t)NT * NB * NH * 2);
    __bf16* SWSa = (__bf16*)carve((size_t)NT * NB * NH * 2);
    __bf16* Z_all = (__bf16*)carve((size_t)NT * NB * NH * 2);
    if (off > ws_size) return;  // fail loudly via absmax if ws too small
    size_t off_save = off;
    float* logitsF = (float*)carve((size_t)NT * NB * NVOC * 4);
    bool useFull = (off <= ws_size);
    if (!useFull) off = off_save;

    // ---- one-time setup ----
    sort_kernel<<<1, NB, 0, stream>>>(cap, w_in, out_target, out_lens, order, lens_s, widx,
                                      live_tb, row_of, counts);
    init_kernel<<<(NB * 5120 + 255) / 256, 256, 0, stream>>>(c, ghh0, ghh1, ghh2, ghh3);
    pack_biases<<<20, 256, 0, stream>>>(b_ih, b_hh, b_xg, b_hg, bh, bs, bstep, b2);
    conv_bf16_vec<<<(NVOC * NEM / 4 + 255) / 256, 256, 0, stream>>>(emb, embb, NVOC * NEM / 4);
    transpose_pack<<<dim3(8, 24), 256, 0, stream>>>(W_glob, 512, 1536, 512, Wglob_t, 1536);
    transpose_pack<<<dim3(16, 24), 256, 0, stream>>>(W_enc, 1024, 1536, 1024, Wenc_t, 1536);
    transpose_pack<<<dim3(16, 16), 256, 0, stream>>>(Wv, 1024, 1024, 1024, Wv_t, 1024);
    transpose_pack<<<dim3(64, 16), 256, 0, stream>>>(W_ih, 4096, 1024, 4096, Wstep_t, 2048);
    transpose_pack<<<dim3(64, 16), 256, 0, stream>>>(W_hh, 4096, 1024, 4096, Wstep_t + 1024, 2048);
    transpose_pack<<<dim3(16, 16), 256, 0, stream>>>(W_xg, 1024, 1024, 1024,
                                                     Wstep_t + (size_t)4096 * 2048, 2048);
    transpose_pack<<<dim3(16, 16), 256, 0, stream>>>(W_hg, 1024, 1024, 1024,
                                                     Wstep_t + (size_t)4096 * 2048 + 1024, 2048);
    transpose_pack<<<dim3(16, 16), 256, 0, stream>>>(Wh, 1024, 1024, 1024, W2t, 1024);
    transpose_pack<<<dim3(16, 16), 256, 0, stream>>>(Ws, 1024, 1024, 1024,
                                                     W2t + (size_t)1024 * 1024, 1024);
    transpose_pack<<<dim3(157, 16), 256, 0, stream>>>(W_out, NVOC, 1024, NVOC, Wout_t, 1024);
    meanim_kernel<<<NB, 256, 0, stream>>>(im, order, meanb);
    conv_perm_kernel<<<(NB * NKK * ND / 8) / 256, 256, 0, stream>>>(im, order, imb);

    // g = relu(meanim @ W_glob + b_glob)
    gemm_k<0, true, true><<<dim3(NEM / BN, 1), 256, 0, stream>>>(
        meanb, ND, Wglob_t, ND, b_glob, g_bf, NEM, NEM, ND, nullptr, nullptr, nullptr,
        0, 0, 0, 0, 0, nullptr, nullptr);
    // V = relu(imb @ W_enc + b_enc), m-panel XCD swizzle
    gemm_k<0, true, true><<<dim3(NH / BN, (NB * NKK) / BM), 256, 0, stream>>>(
        imb, ND, Wenc_t, ND, b_enc, V_bf, NH, NH, ND, nullptr, nullptr, nullptr,
        1, 0, 0, 0, 0, nullptr, nullptr);
    // VA = V @ Wv + bv, m-panel XCD swizzle
    gemm_k<0, false, true><<<dim3(NH / BN, (NB * NKK) / BM), 256, 0, stream>>>(
        V_bf, NH, Wv_t, NH, bv, VA_bf, NH, NH, NH, nullptr, nullptr, nullptr,
        1, 0, 0, 0, 0, nullptr, nullptr);
    // Xpre = [emb|g] @ Wstep_top + bstep  (3840x5120, K=1024), chunk swizzle
    gemm_k<1, false, true><<<dim3(5120 / BN, (NT * NB) / BM), 256, 0, stream>>>(
        nullptr, 0, Wstep_t, 2048, bstep, Xpre, 5120, 5120, 1024, widx, embb, g_bf,
        3, 0, 0, 0, 0, nullptr, nullptr);

    // ---- recurrence: 30 steps ----
    for (int t = 0; t < NT; t++) {
        lstm_kernel<<<128, 256, 0, stream>>>(Xpre, ghh0, ghh1, ghh2, ghh3, c, H_all, S_all, t);
        if (t < NT - 1)
            gatesHH_kernel<<<320, 256, 0, stream>>>(
                H_all + (size_t)t * NB * NH, Wstep_t + 1024, ghh0, ghh1, ghh2, ghh3);
    }

    // ---- batched off-chain tail ----
    gemm_k<0, false, true><<<dim3(NH / BN, NT, 2), 256, 0, stream>>>(
        H_all, NH, W2t, NH, b2, HPa, NH, NH, NH, nullptr, nullptr, nullptr,
        3, (size_t)NT * NB * NH, (size_t)NH * NH, (size_t)NH, (size_t)NT * NB * NH,
        nullptr, nullptr);
    attn_all_kernel<<<NT * NB, 256, 0, stream>>>(VA_bf, V_bf, HPa, SWSa, wa, H_all, S_all,
                                                 Z_all, lens_s);

    if (useFull) {
        // logits on LIVE rows only (gathered), grid worst-case 30 panels, early-exit
        gemm_k<2, false, false><<<dim3(160, NT), 256, 0, stream>>>(
            Z_all, NH, Wout_t, NH, b_out, logitsF, NVOC, NVOC, NH, nullptr, nullptr, nullptr,
            3, 0, 0, 0, 0, live_tb, counts);
        softmax_kernel<true><<<NT * NB, 256, 0, stream>>>(logitsF, lens_s, row_of, pred, 0);
    } else {
        for (int c5 = 0; c5 < NT / CHT; c5++) {
            gemm_k<0, false, false><<<dim3(160, CHT), 256, 0, stream>>>(
                Z_all + (size_t)c5 * CHT * NB * NH, NH, Wout_t, NH, b_out, logitsC, NVOC,
                NVOC, NH, nullptr, nullptr, nullptr, 3, 0, 0, 0, 0, nullptr, nullptr);
            softmax_kernel<false><<<CHT * NB, 256, 0, stream>>>(logitsC, lens_s, nullptr, pred,
                                                                c5 * CHT);
        }
    }
}

// Round 12
// 979.120 us; speedup vs baseline: 1.0768x; 1.0768x over previous
//
#include <hip/hip_runtime.h>
#include <math.h>

#define NB 128
#define NKK 64
#define ND 1536
#define NEM 512
#define NH 1024
#define NVOC 10000
#define NT 30
#define CHT 6

#define BM 128
#define BN 64
#define BK 64

typedef __bf16 bf16x8 __attribute__((ext_vector_type(8)));
typedef __bf16 bf16x4 __attribute__((ext_vector_type(4)));
typedef float f32x4 __attribute__((ext_vector_type(4)));

__device__ __forceinline__ float ftanh(float x) {
    float e = __expf(2.f * x);
    return 1.f - 2.f * __builtin_amdgcn_rcpf(e + 1.f);
}
__device__ __forceinline__ float fsig(float x) {
    return __builtin_amdgcn_rcpf(1.f + __expf(-x));
}

// ---------------- sort + target/lens + widx + live-row map ----------------
__global__ void sort_kernel(const int* __restrict__ cap, const int* __restrict__ w,
                            float* __restrict__ out_target, float* __restrict__ out_lens,
                            int* __restrict__ order, int* __restrict__ lens_s,
                            int* __restrict__ widx, int* __restrict__ live_tb,
                            int* __restrict__ row_of, int* __restrict__ counts) {
    __shared__ int lcap[NB];
    __shared__ int sord[NB];
    __shared__ int slen[NB];
    int b = threadIdx.x;
    lcap[b] = cap[b];
    __syncthreads();
    int lb = lcap[b];
    int pos = 0;
    for (int j = 0; j < NB; j++) {
        int lj = lcap[j];
        if (lj > lb || (lj == lb && j < b)) pos++;
    }
    sord[pos] = b;
    __syncthreads();
    int src = sord[b];
    order[b] = src;
    int ln = lcap[src] - 1;
    lens_s[b] = ln;
    slen[b] = ln;
    out_lens[b] = (float)ln;
    for (int j = 0; j < NT; j++)
        out_target[b * NT + j] = (float)w[src * (NT + 1) + j + 1];
    for (int t = 0; t < NT; t++)
        widx[t * NB + b] = w[src * (NT + 1) + t];
    __syncthreads();
    int prefix = 0;
    for (int j = 0; j < b; j++) prefix += slen[j];
    for (int t = 0; t < ln; t++) {
        row_of[t * NB + b] = prefix + t;
        live_tb[prefix + t] = t * NB + b;
    }
    if (b == NB - 1) {
        int nLive = prefix + ln;
        counts[0] = nLive;
        counts[1] = (nLive + BM - 1) & ~(BM - 1);
    }
}

// ---------------- init c + 4 ghh partials ----------------
__global__ void init_kernel(float* __restrict__ c, float* __restrict__ g0,
                            float* __restrict__ g1, float* __restrict__ g2,
                            float* __restrict__ g3) {
    int tid = blockIdx.x * 256 + threadIdx.x;
    if (tid < NB * NH) c[tid] = 0.f;
    if (tid < NB * 5120) { g0[tid] = 0.f; g1[tid] = 0.f; g2[tid] = 0.f; g3[tid] = 0.f; }
}

// ---------------- mean over K (sorted order), bf16 out ----------------
__global__ void meanim_kernel(const float* __restrict__ im, const int* __restrict__ order,
                              __bf16* __restrict__ meanb) {
    int b = blockIdx.x;
    int src = order[b];
    const float* base = im + (size_t)src * NKK * ND;
    for (int d = threadIdx.x; d < ND; d += 256) {
        float acc = 0.f;
        for (int k = 0; k < NKK; k++) acc += base[(size_t)k * ND + d];
        meanb[b * ND + d] = (__bf16)(acc * (1.0f / NKK));
    }
}

// ---------------- permuted f32 -> bf16 of im ----------------
__global__ void conv_perm_kernel(const float* __restrict__ im, const int* __restrict__ order,
                                 __bf16* __restrict__ imb) {
    int e8 = blockIdx.x * 256 + threadIdx.x;
    size_t elem = (size_t)e8 * 8;
    int bp = (int)(elem / (NKK * ND));
    size_t rem = elem % (NKK * ND);
    const float* src = im + (size_t)order[bp] * NKK * ND + rem;
    float4 f0 = *(const float4*)(src);
    float4 f1 = *(const float4*)(src + 4);
    bf16x8 v = {(__bf16)f0.x, (__bf16)f0.y, (__bf16)f0.z, (__bf16)f0.w,
                (__bf16)f1.x, (__bf16)f1.y, (__bf16)f1.z, (__bf16)f1.w};
    *(bf16x8*)(imb + elem) = v;
}

// ---------------- LDS-tiled transpose + f32->bf16 pack ----------------
__global__ __launch_bounds__(256) void transpose_pack(
    const float* __restrict__ src, int ldn, int K, int N,
    __bf16* __restrict__ dst, int ldk) {
    __shared__ float tile[64][65];
    int k0 = blockIdx.y * 64, n0 = blockIdx.x * 64;
    int t = threadIdx.x;
    int kr = t >> 2, nc0 = (t & 3) * 16;
    int kk = k0 + kr;
#pragma unroll
    for (int j = 0; j < 16; j += 4) {
        int nn = n0 + nc0 + j;
        float4 v = make_float4(0.f, 0.f, 0.f, 0.f);
        if (kk < K && nn + 3 < N) v = *(const float4*)(src + (size_t)kk * ldn + nn);
        else if (kk < K) {
            float tmp[4] = {0.f, 0.f, 0.f, 0.f};
            for (int q = 0; q < 4; q++) if (nn + q < N) tmp[q] = src[(size_t)kk * ldn + nn + q];
            v = make_float4(tmp[0], tmp[1], tmp[2], tmp[3]);
        }
        tile[kr][nc0 + j + 0] = v.x; tile[kr][nc0 + j + 1] = v.y;
        tile[kr][nc0 + j + 2] = v.z; tile[kr][nc0 + j + 3] = v.w;
    }
    __syncthreads();
    int nr = t >> 2, kc0 = (t & 3) * 16;
    if (n0 + nr < N) {
        __bf16* drow = dst + (size_t)(n0 + nr) * ldk + k0 + kc0;
#pragma unroll
        for (int j = 0; j < 16; j++)
            if (k0 + kc0 + j < K) drow[j] = (__bf16)tile[kc0 + j][nr];
    }
}

// ---------------- f32 -> bf16 vector convert ----------------
__global__ void conv_bf16_vec(const float* __restrict__ src, __bf16* __restrict__ dst, int n4) {
    int id = blockIdx.x * 256 + threadIdx.x;
    if (id < n4) {
        float4 v = *(const float4*)(src + (size_t)id * 4);
        __bf16* d = dst + (size_t)id * 4;
        d[0] = (__bf16)v.x; d[1] = (__bf16)v.y; d[2] = (__bf16)v.z; d[3] = (__bf16)v.w;
    }
}

// ---------------- bias packs ----------------
__global__ void pack_biases(const float* __restrict__ b_ih, const float* __restrict__ b_hh,
                            const float* __restrict__ b_xg, const float* __restrict__ b_hg,
                            const float* __restrict__ bh, const float* __restrict__ bs,
                            float* __restrict__ bstep, float* __restrict__ b2) {
    int i = blockIdx.x * 256 + threadIdx.x;
    if (i < 4096) bstep[i] = b_ih[i] + b_hh[i];
    else bstep[i] = b_xg[i - 4096] + b_hg[i - 4096];
    if (i < 1024) b2[i] = bh[i];
    else if (i < 2048) b2[i] = bs[i - 1024];
}

// =======================================================================
// gemm_k: MFMA GEMM (proven R3 core), z-batch strides.
// AMODE 0: bf16 A direct. AMODE 1: x-concat. AMODE 2: live-row gather.
// swz: 0 none; 1 m-panel-grouped (gridY%8==0);
//      4 n-chunked/m-minor: XCD owns gx/8 contiguous n-blocks, walks all
//        m-panels (gridX%8==0) — balanced under m-panel early-exit.
// cnts != nullptr: skip blocks whose m-panel is past cnts[1] (padded live).
// =======================================================================
template <int AMODE, bool RELU, bool OUTBF>
__global__ __launch_bounds__(256) void gemm_k(
    const void* __restrict__ Aptr, int lda,
    const __bf16* __restrict__ Bt, int ldb,
    const float* __restrict__ bias,
    void* __restrict__ Cptr, int ldc,
    int N, int K,
    const int* __restrict__ widx,
    const __bf16* __restrict__ embb, const __bf16* __restrict__ gbf,
    int swz, size_t sA, size_t sB, size_t sBias, size_t sC,
    const int* __restrict__ live_tb, const int* __restrict__ cnts) {
    const int t = threadIdx.x;
    const int lane = t & 63;
    const int wid = t >> 6;
    const int wr = wid >> 1, wc = wid & 1;
    int bx = blockIdx.x, by = blockIdx.y;
    if (swz == 1) {
        int L = by * gridDim.x + bx;
        int xcd = L & 7, q = L >> 3;
        by = xcd * (gridDim.y >> 3) + q / gridDim.x;
        bx = q % gridDim.x;
    } else if (swz == 4) {
        int L = by * gridDim.x + bx;
        int xcd = L & 7, idx = L >> 3;
        int nbx = gridDim.x >> 3;
        bx = xcd * nbx + idx % nbx;
        by = idx / nbx;
    }
    const int z = blockIdx.z;
    const int m0 = by * BM;
    const int n0 = bx * BN;
    if (cnts && m0 >= cnts[1]) return;
    const int lr = lane & 15, lg = lane >> 4, lr8 = lr & 7;

    __shared__ __bf16 As[BM * BK];
    __shared__ __bf16 Bs[BN * BK];

    f32x4 acc[4][2];
#pragma unroll
    for (int i = 0; i < 4; i++)
#pragma unroll
        for (int j = 0; j < 2; j++) acc[i][j] = (f32x4){0.f, 0.f, 0.f, 0.f};

    const int s_row = t >> 1;
    const int s_g0 = (t & 1) * 4;
    const int s_col = t >> 2;
    const int s_bg0 = (t & 3) * 2;
    const int r8 = s_row & 7, c8 = s_col & 7;
    const int aw0 = (s_row << 6) + (((s_g0 + 0) ^ r8) << 3);
    const int aw1 = (s_row << 6) + (((s_g0 + 1) ^ r8) << 3);
    const int aw2 = (s_row << 6) + (((s_g0 + 2) ^ r8) << 3);
    const int aw3 = (s_row << 6) + (((s_g0 + 3) ^ r8) << 3);
    const int bw0 = (s_col << 6) + (((s_bg0 + 0) ^ c8) << 3);
    const int bw1 = (s_col << 6) + (((s_bg0 + 1) ^ c8) << 3);
    const int rA0 = (wr * 64 + 0 * 16 + lr) << 6;
    const int rA1 = (wr * 64 + 1 * 16 + lr) << 6;
    const int rA2 = (wr * 64 + 2 * 16 + lr) << 6;
    const int rA3 = (wr * 64 + 3 * 16 + lr) << 6;
    const int cB0 = (wc * 32 + 0 * 16 + lr) << 6;
    const int cB1 = (wc * 32 + 1 * 16 + lr) << 6;

    const __bf16* a_srcb = nullptr;
    const __bf16* e_base = nullptr;
    const __bf16* g_base = nullptr;
    if (AMODE == 1) {
        int r = m0 + s_row;
        e_base = embb + (size_t)widx[r] * NEM + s_g0 * 8;
        g_base = gbf + (size_t)(r & 127) * NEM + s_g0 * 8 - NEM;
    } else if (AMODE == 2) {
        int r = m0 + s_row;
        int nl = cnts[0];
        int rr = r < nl ? r : nl - 1;
        a_srcb = (const __bf16*)Aptr + z * sA + (size_t)live_tb[rr] * lda + s_g0 * 8;
    } else {
        a_srcb = (const __bf16*)Aptr + z * sA + (size_t)(m0 + s_row) * lda + s_g0 * 8;
    }
    const __bf16* b_src = Bt + z * sB + (size_t)(n0 + s_col) * ldb + s_bg0 * 8;
    const bool b_ok = (n0 + s_col) < N;

    auto loadA = [&](int k0, bf16x8& a0, bf16x8& a1, bf16x8& a2, bf16x8& a3) {
        if (AMODE == 1) {
            int kk = k0 + s_g0 * 8;
            const bf16x8* p = (const bf16x8*)((kk < NEM ? e_base : g_base) + k0);
            a0 = p[0]; a1 = p[1]; a2 = p[2]; a3 = p[3];
        } else {
            const bf16x8* p = (const bf16x8*)(a_srcb + k0);
            a0 = p[0]; a1 = p[1]; a2 = p[2]; a3 = p[3];
        }
    };
    auto loadB = [&](int k0, bf16x8& b0, bf16x8& b1) {
        if (b_ok) {
            const bf16x8* p = (const bf16x8*)(b_src + k0);
            b0 = p[0]; b1 = p[1];
        } else {
            bf16x8 zv = {};
            b0 = zv; b1 = zv;
        }
    };
    auto writeS = [&](bf16x8 a0, bf16x8 a1, bf16x8 a2, bf16x8 a3, bf16x8 b0, bf16x8 b1) {
        *(bf16x8*)&As[aw0] = a0; *(bf16x8*)&As[aw1] = a1;
        *(bf16x8*)&As[aw2] = a2; *(bf16x8*)&As[aw3] = a3;
        *(bf16x8*)&Bs[bw0] = b0; *(bf16x8*)&Bs[bw1] = b1;
    };
    auto compute = [&]() {
#pragma unroll
        for (int ks = 0; ks < 2; ks++) {
            const int gsw = ((ks * 4 + lg) ^ lr8) << 3;
            bf16x8 af0 = *(const bf16x8*)&As[rA0 + gsw];
            bf16x8 af1 = *(const bf16x8*)&As[rA1 + gsw];
            bf16x8 af2 = *(const bf16x8*)&As[rA2 + gsw];
            bf16x8 af3 = *(const bf16x8*)&As[rA3 + gsw];
            bf16x8 bv0 = *(const bf16x8*)&Bs[cB0 + gsw];
            bf16x8 bv1 = *(const bf16x8*)&Bs[cB1 + gsw];
            acc[0][0] = __builtin_amdgcn_mfma_f32_16x16x32_bf16(af0, bv0, acc[0][0], 0, 0, 0);
            acc[0][1] = __builtin_amdgcn_mfma_f32_16x16x32_bf16(af0, bv1, acc[0][1], 0, 0, 0);
            acc[1][0] = __builtin_amdgcn_mfma_f32_16x16x32_bf16(af1, bv0, acc[1][0], 0, 0, 0);
            acc[1][1] = __builtin_amdgcn_mfma_f32_16x16x32_bf16(af1, bv1, acc[1][1], 0, 0, 0);
            acc[2][0] = __builtin_amdgcn_mfma_f32_16x16x32_bf16(af2, bv0, acc[2][0], 0, 0, 0);
            acc[2][1] = __builtin_amdgcn_mfma_f32_16x16x32_bf16(af2, bv1, acc[2][1], 0, 0, 0);
            acc[3][0] = __builtin_amdgcn_mfma_f32_16x16x32_bf16(af3, bv0, acc[3][0], 0, 0, 0);
            acc[3][1] = __builtin_amdgcn_mfma_f32_16x16x32_bf16(af3, bv1, acc[3][1], 0, 0, 0);
        }
    };

    bf16x8 a0, a1, a2, a3, b0, b1;
    bf16x8 c0, c1, c2, c3, d0, d1;
    loadA(0, a0, a1, a2, a3);
    loadB(0, b0, b1);
    for (int k0 = 0; k0 < K; k0 += 2 * BK) {
        writeS(a0, a1, a2, a3, b0, b1);
        __syncthreads();
        loadA(k0 + BK, c0, c1, c2, c3);
        loadB(k0 + BK, d0, d1);
        compute();
        __syncthreads();
        writeS(c0, c1, c2, c3, d0, d1);
        __syncthreads();
        if (k0 + 2 * BK < K) {
            loadA(k0 + 2 * BK, a0, a1, a2, a3);
            loadB(k0 + 2 * BK, b0, b1);
        }
        compute();
        __syncthreads();
    }

    const float* bias_z = bias + z * sBias;
    float* Cf = (float*)Cptr + z * sC;
    __bf16* Cb = (__bf16*)Cptr + z * sC;
#pragma unroll
    for (int mi = 0; mi < 4; mi++) {
#pragma unroll
        for (int ni = 0; ni < 2; ni++) {
            int col = n0 + wc * 32 + ni * 16 + lr;
            if (col < N) {
                float bb = bias_z[col];
#pragma unroll
                for (int rr = 0; rr < 4; rr++) {
                    int row = m0 + wr * 64 + mi * 16 + lg * 4 + rr;
                    float v = acc[mi][ni][rr] + bb;
                    if (RELU) v = fmaxf(v, 0.f);
                    if (OUTBF) Cb[(size_t)row * ldc + col] = (__bf16)v;
                    else Cf[(size_t)row * ldc + col] = v;
                }
            }
        }
    }
}

// =======================================================================
// step_gemm: device core (M=128, bf16 A, f32 out, nullable bias)
// =======================================================================
__device__ __forceinline__ void step_gemm(
    __bf16* As, __bf16* Bs,
    const __bf16* __restrict__ Ab, int lda,
    const __bf16* __restrict__ Bt, int ldb,
    const float* __restrict__ bias,
    float* __restrict__ C, int ldc, int N, int n0, int K) {
    const int t = threadIdx.x;
    const int lane = t & 63;
    const int wid = t >> 6;
    const int wr = wid >> 1, wc = wid & 1;
    const int lr = lane & 15, lg = lane >> 4, lr8 = lr & 7;

    f32x4 acc[4][2];
#pragma unroll
    for (int i = 0; i < 4; i++)
#pragma unroll
        for (int j = 0; j < 2; j++) acc[i][j] = (f32x4){0.f, 0.f, 0.f, 0.f};

    const int s_row = t >> 1;
    const int s_g0 = (t & 1) * 4;
    const int s_col = t >> 2;
    const int s_bg0 = (t & 3) * 2;
    const int r8 = s_row & 7, c8 = s_col & 7;
    const int aw0 = (s_row << 6) + (((s_g0 + 0) ^ r8) << 3);
    const int aw1 = (s_row << 6) + (((s_g0 + 1) ^ r8) << 3);
    const int aw2 = (s_row << 6) + (((s_g0 + 2) ^ r8) << 3);
    const int aw3 = (s_row << 6) + (((s_g0 + 3) ^ r8) << 3);
    const int bw0 = (s_col << 6) + (((s_bg0 + 0) ^ c8) << 3);
    const int bw1 = (s_col << 6) + (((s_bg0 + 1) ^ c8) << 3);
    const int rA0 = (wr * 64 + 0 * 16 + lr) << 6;
    const int rA1 = (wr * 64 + 1 * 16 + lr) << 6;
    const int rA2 = (wr * 64 + 2 * 16 + lr) << 6;
    const int rA3 = (wr * 64 + 3 * 16 + lr) << 6;
    const int cB0 = (wc * 32 + 0 * 16 + lr) << 6;
    const int cB1 = (wc * 32 + 1 * 16 + lr) << 6;

    const __bf16* a_src = Ab + (size_t)s_row * lda + s_g0 * 8;
    const __bf16* b_src = Bt + (size_t)(n0 + s_col) * ldb + s_bg0 * 8;
    const bool b_ok = (n0 + s_col) < N;

    auto loadA = [&](int k0, bf16x8& a0, bf16x8& a1, bf16x8& a2, bf16x8& a3) {
        const bf16x8* p = (const bf16x8*)(a_src + k0);
        a0 = p[0]; a1 = p[1]; a2 = p[2]; a3 = p[3];
    };
    auto loadB = [&](int k0, bf16x8& b0, bf16x8& b1) {
        if (b_ok) {
            const bf16x8* p = (const bf16x8*)(b_src + k0);
            b0 = p[0]; b1 = p[1];
        } else {
            bf16x8 zv = {};
            b0 = zv; b1 = zv;
        }
    };
    auto writeS = [&](bf16x8 a0, bf16x8 a1, bf16x8 a2, bf16x8 a3, bf16x8 b0, bf16x8 b1) {
        *(bf16x8*)&As[aw0] = a0; *(bf16x8*)&As[aw1] = a1;
        *(bf16x8*)&As[aw2] = a2; *(bf16x8*)&As[aw3] = a3;
        *(bf16x8*)&Bs[bw0] = b0; *(bf16x8*)&Bs[bw1] = b1;
    };
    auto compute = [&]() {
#pragma unroll
        for (int ks = 0; ks < 2; ks++) {
            const int gsw = ((ks * 4 + lg) ^ lr8) << 3;
            bf16x8 af0 = *(const bf16x8*)&As[rA0 + gsw];
            bf16x8 af1 = *(const bf16x8*)&As[rA1 + gsw];
            bf16x8 af2 = *(const bf16x8*)&As[rA2 + gsw];
            bf16x8 af3 = *(const bf16x8*)&As[rA3 + gsw];
            bf16x8 bv0 = *(const bf16x8*)&Bs[cB0 + gsw];
            bf16x8 bv1 = *(const bf16x8*)&Bs[cB1 + gsw];
            acc[0][0] = __builtin_amdgcn_mfma_f32_16x16x32_bf16(af0, bv0, acc[0][0], 0, 0, 0);
            acc[0][1] = __builtin_amdgcn_mfma_f32_16x16x32_bf16(af0, bv1, acc[0][1], 0, 0, 0);
            acc[1][0] = __builtin_amdgcn_mfma_f32_16x16x32_bf16(af1, bv0, acc[1][0], 0, 0, 0);
            acc[1][1] = __builtin_amdgcn_mfma_f32_16x16x32_bf16(af1, bv1, acc[1][1], 0, 0, 0);
            acc[2][0] = __builtin_amdgcn_mfma_f32_16x16x32_bf16(af2, bv0, acc[2][0], 0, 0, 0);
            acc[2][1] = __builtin_amdgcn_mfma_f32_16x16x32_bf16(af2, bv1, acc[2][1], 0, 0, 0);
            acc[3][0] = __builtin_amdgcn_mfma_f32_16x16x32_bf16(af3, bv0, acc[3][0], 0, 0, 0);
            acc[3][1] = __builtin_amdgcn_mfma_f32_16x16x32_bf16(af3, bv1, acc[3][1], 0, 0, 0);
        }
    };

    bf16x8 a0, a1, a2, a3, b0, b1;
    bf16x8 c0, c1, c2, c3, d0, d1;
    loadA(0, a0, a1, a2, a3);
    loadB(0, b0, b1);
    for (int k0 = 0; k0 < K; k0 += 2 * BK) {
        writeS(a0, a1, a2, a3, b0, b1);
        __syncthreads();
        loadA(k0 + BK, c0, c1, c2, c3);
        loadB(k0 + BK, d0, d1);
        compute();
        __syncthreads();
        writeS(c0, c1, c2, c3, d0, d1);
        __syncthreads();
        if (k0 + 2 * BK < K) {
            loadA(k0 + 2 * BK, a0, a1, a2, a3);
            loadB(k0 + 2 * BK, b0, b1);
        }
        compute();
        __syncthreads();
    }

#pragma unroll
    for (int mi = 0; mi < 4; mi++) {
#pragma unroll
        for (int ni = 0; ni < 2; ni++) {
            int col = n0 + wc * 32 + ni * 16 + lr;
            if (col < N) {
                float bb = bias ? bias[col] : 0.f;
#pragma unroll
                for (int rr = 0; rr < 4; rr++) {
                    int row = wr * 64 + mi * 16 + lg * 4 + rr;
                    C[(size_t)row * ldc + col] = acc[mi][ni][rr] + bb;
                }
            }
        }
    }
}

// =======================================================================
// lstm: per-step pointwise; sums 4 ghh partials
// =======================================================================
__global__ __launch_bounds__(256) void lstm_kernel(
    const __bf16* __restrict__ Xpre, const float* __restrict__ g0,
    const float* __restrict__ g1, const float* __restrict__ g2,
    const float* __restrict__ g3, float* __restrict__ c,
    __bf16* __restrict__ H_all, __bf16* __restrict__ S_all, int t) {
    int i4 = (blockIdx.x * 256 + threadIdx.x) * 4;
    int b = i4 >> 10, j = i4 & 1023;
    const __bf16* xp = Xpre + ((size_t)t * NB + b) * 5120 + j;
    size_t gof = (size_t)b * 5120 + j;
    float4 cv = *(const float4*)(c + i4);
    float cvp[4] = {cv.x, cv.y, cv.z, cv.w};
    float pre[5][4];
#pragma unroll
    for (int q = 0; q < 5; q++) {
        bf16x4 xv = *(const bf16x4*)(xp + q * 1024);
        float4 a0 = *(const float4*)(g0 + gof + q * 1024);
        float4 a1 = *(const float4*)(g1 + gof + q * 1024);
        float4 a2 = *(const float4*)(g2 + gof + q * 1024);
        float4 a3 = *(const float4*)(g3 + gof + q * 1024);
        pre[q][0] = (float)xv[0] + a0.x + a1.x + a2.x + a3.x;
        pre[q][1] = (float)xv[1] + a0.y + a1.y + a2.y + a3.y;
        pre[q][2] = (float)xv[2] + a0.z + a1.z + a2.z + a3.z;
        pre[q][3] = (float)xv[3] + a0.w + a1.w + a2.w + a3.w;
    }
    float cn4[4];
    bf16x4 hv, sv;
#pragma unroll
    for (int e = 0; e < 4; e++) {
        float cn = fsig(pre[1][e]) * cvp[e] + fsig(pre[0][e]) * ftanh(pre[2][e]);
        float tc = ftanh(cn);
        cn4[e] = cn;
        hv[e] = (__bf16)(fsig(pre[3][e]) * tc);
        sv[e] = (__bf16)(fsig(pre[4][e]) * tc);
    }
    *(float4*)(c + i4) = make_float4(cn4[0], cn4[1], cn4[2], cn4[3]);
    *(bf16x4*)(H_all + (size_t)t * NB * NH + i4) = hv;
    *(bf16x4*)(S_all + (size_t)t * NB * NH + i4) = sv;
}

// =======================================================================
// gatesHH: ghh = h_t @ [W_hh|W_hg] (split-K 4, 320 blocks)
// =======================================================================
__global__ __launch_bounds__(256) void gatesHH_kernel(
    const __bf16* __restrict__ H_t, const __bf16* __restrict__ Whh,
    float* __restrict__ g0, float* __restrict__ g1,
    float* __restrict__ g2, float* __restrict__ g3) {
    __shared__ __bf16 As[BM * BK];
    __shared__ __bf16 Bs[BN * BK];
    int kc = blockIdx.x & 3, n = blockIdx.x >> 2;
    float* outp = (kc == 0) ? g0 : (kc == 1) ? g1 : (kc == 2) ? g2 : g3;
    step_gemm(As, Bs, H_t + kc * 256, NH, Whh + kc * 256, 2048, nullptr,
              outp, 5120, 5120, n * 64, 256);
}

// =======================================================================
// attn_all: one block per COMPACT row r; Z written compact.
// =======================================================================
__global__ __launch_bounds__(256) void attn_all_kernel(
    const __bf16* __restrict__ VA, const __bf16* __restrict__ V,
    const __bf16* __restrict__ HPa, const __bf16* __restrict__ SWSa,
    const float* __restrict__ wa, const __bf16* __restrict__ H_all,
    const __bf16* __restrict__ S_all, __bf16* __restrict__ Z_all,
    const int* __restrict__ live_tb, const int* __restrict__ cnts) {
    __shared__ float zscore[NKK + 1];
    __shared__ float alpha_s[NKK + 1];
    int r = blockIdx.x;
    if (r >= cnts[0]) return;
    int tb = live_tb[r];
    int b = tb & 127;
    int wave = threadIdx.x >> 6, lane = threadIdx.x & 63;

    float hp_reg[16], wa_reg[16];
    {
        const bf16x8* hr = (const bf16x8*)(HPa + (size_t)r * NH + lane * 16);
        bf16x8 h0 = hr[0], h1 = hr[1];
        const float* wb = wa + lane * 16;
#pragma unroll
        for (int q = 0; q < 4; q++) {
            float4 wv = *(const float4*)(wb + q * 4);
            wa_reg[q * 4 + 0] = wv.x; wa_reg[q * 4 + 1] = wv.y;
            wa_reg[q * 4 + 2] = wv.z; wa_reg[q * 4 + 3] = wv.w;
        }
#pragma unroll
        for (int j = 0; j < 8; j++) { hp_reg[j] = (float)h0[j]; hp_reg[8 + j] = (float)h1[j]; }
    }
    for (int k = wave; k <= NKK; k += 4) {
        float p = 0.f;
        if (k < NKK) {
            const bf16x8* row = (const bf16x8*)(VA + ((size_t)(b * NKK + k)) * NH + lane * 16);
            bf16x8 v0 = row[0], v1 = row[1];
#pragma unroll
            for (int j = 0; j < 8; j++) {
                p += ftanh((float)v0[j] + hp_reg[j]) * wa_reg[j];
                p += ftanh((float)v1[j] + hp_reg[8 + j]) * wa_reg[8 + j];
            }
        } else {
            const bf16x8* sr = (const bf16x8*)(SWSa + (size_t)r * NH + lane * 16);
            bf16x8 s0 = sr[0], s1 = sr[1];
#pragma unroll
            for (int j = 0; j < 8; j++) {
                p += ftanh((float)s0[j] + hp_reg[j]) * wa_reg[j];
                p += ftanh((float)s1[j] + hp_reg[8 + j]) * wa_reg[8 + j];
            }
        }
        for (int off = 32; off; off >>= 1) p += __shfl_down(p, off);
        if (lane == 0) zscore[k] = p;
    }
    __syncthreads();
    if (threadIdx.x == 0) {
        float mx = zscore[0];
        for (int i = 1; i <= NKK; i++) mx = fmaxf(mx, zscore[i]);
        float ssum = 0.f;
        for (int i = 0; i <= NKK; i++) { float e = __expf(zscore[i] - mx); alpha_s[i] = e; ssum += e; }
        float inv = __builtin_amdgcn_rcpf(ssum);
        for (int i = 0; i <= NKK; i++) alpha_s[i] *= inv;
    }
    __syncthreads();
    float beta = alpha_s[NKK];
    {
        int jj0 = threadIdx.x * 4;
        const __bf16* vp = V + ((size_t)b * NKK) * NH + jj0;
        float c0 = 0.f, c1 = 0.f, c2 = 0.f, c3 = 0.f;
#pragma unroll 8
        for (int k = 0; k < NKK; k++) {
            bf16x4 vv = *(const bf16x4*)(vp + (size_t)k * NH);
            float a = alpha_s[k];
            c0 += a * (float)vv[0]; c1 += a * (float)vv[1];
            c2 += a * (float)vv[2]; c3 += a * (float)vv[3];
        }
        bf16x4 s4 = *(const bf16x4*)(S_all + (size_t)tb * NH + jj0);
        bf16x4 h4 = *(const bf16x4*)(H_all + (size_t)tb * NH + jj0);
        float ob = 1.f - beta;
        bf16x4 zv;
        zv[0] = (__bf16)(beta * (float)s4[0] + ob * c0 + (float)h4[0]);
        zv[1] = (__bf16)(beta * (float)s4[1] + ob * c1 + (float)h4[1]);
        zv[2] = (__bf16)(beta * (float)s4[2] + ob * c2 + (float)h4[2]);
        zv[3] = (__bf16)(beta * (float)s4[3] + ob * c3 + (float)h4[3]);
        *(bf16x4*)(Z_all + (size_t)r * NH + jj0) = zv;
    }
}

// =======================================================================
// softmax over vocab; COMPACT: logits row via row_of; else dense rows.
// =======================================================================
template <bool COMPACT>
__global__ __launch_bounds__(256) void softmax_kernel(
    const float* __restrict__ logitsB, const int* __restrict__ lens,
    const int* __restrict__ row_of, float* __restrict__ pred, int t0) {
    __shared__ float se[NVOC];
    __shared__ float sred[4], sred2[4];
    int r = blockIdx.x;
    int tt = r >> 7, b = r & 127;
    int t = t0 + tt;
    float* out = pred + (size_t)b * NT * NVOC + (size_t)t * NVOC;
    if (t >= lens[b]) {
        for (int v = threadIdx.x; v < NVOC; v += 256) out[v] = 0.f;
        return;
    }
    size_t srcrow = COMPACT ? (size_t)row_of[t * NB + b] : (size_t)r;
    const float* lg = logitsB + srcrow * NVOC;
    float mx = -1e30f;
    for (int v = threadIdx.x; v < NVOC; v += 256) {
        float x = lg[v];
        se[v] = x;
        mx = fmaxf(mx, x);
    }
    for (int off = 32; off; off >>= 1) mx = fmaxf(mx, __shfl_down(mx, off));
    if ((threadIdx.x & 63) == 0) sred[threadIdx.x >> 6] = mx;
    __syncthreads();
    mx = fmaxf(fmaxf(sred[0], sred[1]), fmaxf(sred[2], sred[3]));
    float ssum = 0.f;
    for (int v = threadIdx.x; v < NVOC; v += 256) {
        float e = __expf(se[v] - mx);
        se[v] = e;
        ssum += e;
    }
    for (int off = 32; off; off >>= 1) ssum += __shfl_down(ssum, off);
    if ((threadIdx.x & 63) == 0) sred2[threadIdx.x >> 6] = ssum;
    __syncthreads();
    ssum = sred2[0] + sred2[1] + sred2[2] + sred2[3];
    float inv = 1.f / ssum;
    for (int v = threadIdx.x; v < NVOC; v += 256) out[v] = se[v] * inv;
}

extern "C" void kernel_launch(void* const* d_in, const int* in_sizes, int n_in,
                              void* d_out, int out_size, void* d_ws, size_t ws_size,
                              hipStream_t stream) {
    const float* im = (const float*)d_in[0];
    const int* w_in = (const int*)d_in[1];
    const int* cap = (const int*)d_in[2];
    const float* emb = (const float*)d_in[3];
    const float* W_enc = (const float*)d_in[4];
    const float* b_enc = (const float*)d_in[5];
    const float* W_glob = (const float*)d_in[6];
    const float* b_glob = (const float*)d_in[7];
    const float* W_ih = (const float*)d_in[8];
    const float* b_ih = (const float*)d_in[9];
    const float* W_hh = (const float*)d_in[10];
    const float* b_hh = (const float*)d_in[11];
    const float* W_xg = (const float*)d_in[12];
    const float* b_xg = (const float*)d_in[13];
    const float* W_hg = (const float*)d_in[14];
    const float* b_hg = (const float*)d_in[15];
    const float* Wv = (const float*)d_in[16];
    const float* bv = (const float*)d_in[17];
    const float* Ws = (const float*)d_in[18];
    const float* bs = (const float*)d_in[19];
    const float* Wh = (const float*)d_in[20];
    const float* bh = (const float*)d_in[21];
    const float* wa = (const float*)d_in[22];
    // ba cancels in softmax(65)
    const float* W_out = (const float*)d_in[24];
    const float* b_out = (const float*)d_in[25];

    float* out = (float*)d_out;
    float* pred = out;
    float* out_target = out + (size_t)NB * NT * NVOC;
    float* out_lens = out_target + NB * NT;

    char* p = (char*)d_ws;
    size_t off = 0;
    auto carve = [&](size_t bytes) {
        void* r = p + off;
        off += (bytes + 255) & ~(size_t)255;
        return r;
    };
    int* order = (int*)carve(NB * 4);
    int* lens_s = (int*)carve(NB * 4);
    int* widx = (int*)carve(NT * NB * 4);
    int* live_tb = (int*)carve(NT * NB * 4);
    int* row_of = (int*)carve(NT * NB * 4);
    int* counts = (int*)carve(2 * 4);
    __bf16* embb = (__bf16*)carve((size_t)NVOC * NEM * 2);
    __bf16* Wstep_t = (__bf16*)carve((size_t)5120 * 2048 * 2);
    __bf16* W2t = (__bf16*)carve((size_t)2 * 1024 * 1024 * 2);
    __bf16* Wout_t = (__bf16*)carve((size_t)NVOC * 1024 * 2);
    __bf16* Wglob_t = (__bf16*)carve((size_t)512 * 1536 * 2);
    __bf16* Wenc_t = (__bf16*)carve((size_t)1024 * 1536 * 2);
    __bf16* Wv_t = (__bf16*)carve((size_t)1024 * 1024 * 2);
    float* bstep = (float*)carve(5120 * 4);
    float* b2 = (float*)carve(2048 * 4);
    __bf16* meanb = (__bf16*)carve((size_t)NB * ND * 2);
    __bf16* g_bf = (__bf16*)carve((size_t)NB * NEM * 2);
    __bf16* V_bf = (__bf16*)carve((size_t)NB * NKK * NH * 2);
    __bf16* VA_bf = (__bf16*)carve((size_t)NB * NKK * NH * 2);
    void* uni = carve((size_t)NT * NB * 5120 * 2);
    __bf16* imb = (__bf16*)uni;
    __bf16* Xpre = (__bf16*)uni;
    float* logitsC = (float*)uni;
    float* ghh0 = (float*)carve((size_t)NB * 5120 * 4);
    float* ghh1 = (float*)carve((size_t)NB * 5120 * 4);
    float* ghh2 = (float*)carve((size_t)NB * 5120 * 4);
    float* ghh3 = (float*)carve((size_t)NB * 5120 * 4);
    float* c = (float*)carve((size_t)NB * NH * 4);
    __bf16* H_all = (__bf16*)carve((size_t)NT * NB * NH * 2);
    __bf16* S_all = (__bf16*)carve((size_t)NT * NB * NH * 2);
    __bf16* HPa = (__bf16*)carve((size_t)NT * NB * NH * 2);
    __bf16* SWSa = (__bf16*)carve((size_t)NT * NB * NH * 2);
    __bf16* Z_all = (__bf16*)carve((size_t)NT * NB * NH * 2);
    if (off > ws_size) return;  // fail loudly via absmax if ws too small
    size_t off_save = off;
    float* logitsF = (float*)carve((size_t)NT * NB * NVOC * 4);
    bool useFull = (off <= ws_size);
    if (!useFull) off = off_save;

    // ---- one-time setup ----
    sort_kernel<<<1, NB, 0, stream>>>(cap, w_in, out_target, out_lens, order, lens_s, widx,
                                      live_tb, row_of, counts);
    init_kernel<<<(NB * 5120 + 255) / 256, 256, 0, stream>>>(c, ghh0, ghh1, ghh2, ghh3);
    pack_biases<<<20, 256, 0, stream>>>(b_ih, b_hh, b_xg, b_hg, bh, bs, bstep, b2);
    conv_bf16_vec<<<(NVOC * NEM / 4 + 255) / 256, 256, 0, stream>>>(emb, embb, NVOC * NEM / 4);
    transpose_pack<<<dim3(8, 24), 256, 0, stream>>>(W_glob, 512, 1536, 512, Wglob_t, 1536);
    transpose_pack<<<dim3(16, 24), 256, 0, stream>>>(W_enc, 1024, 1536, 1024, Wenc_t, 1536);
    transpose_pack<<<dim3(16, 16), 256, 0, stream>>>(Wv, 1024, 1024, 1024, Wv_t, 1024);
    transpose_pack<<<dim3(64, 16), 256, 0, stream>>>(W_ih, 4096, 1024, 4096, Wstep_t, 2048);
    transpose_pack<<<dim3(64, 16), 256, 0, stream>>>(W_hh, 4096, 1024, 4096, Wstep_t + 1024, 2048);
    transpose_pack<<<dim3(16, 16), 256, 0, stream>>>(W_xg, 1024, 1024, 1024,
                                                     Wstep_t + (size_t)4096 * 2048, 2048);
    transpose_pack<<<dim3(16, 16), 256, 0, stream>>>(W_hg, 1024, 1024, 1024,
                                                     Wstep_t + (size_t)4096 * 2048 + 1024, 2048);
    transpose_pack<<<dim3(16, 16), 256, 0, stream>>>(Wh, 1024, 1024, 1024, W2t, 1024);
    transpose_pack<<<dim3(16, 16), 256, 0, stream>>>(Ws, 1024, 1024, 1024,
                                                     W2t + (size_t)1024 * 1024, 1024);
    transpose_pack<<<dim3(157, 16), 256, 0, stream>>>(W_out, NVOC, 1024, NVOC, Wout_t, 1024);
    meanim_kernel<<<NB, 256, 0, stream>>>(im, order, meanb);
    conv_perm_kernel<<<(NB * NKK * ND / 8) / 256, 256, 0, stream>>>(im, order, imb);

    // g = relu(meanim @ W_glob + b_glob)
    gemm_k<0, true, true><<<dim3(NEM / BN, 1), 256, 0, stream>>>(
        meanb, ND, Wglob_t, ND, b_glob, g_bf, NEM, NEM, ND, nullptr, nullptr, nullptr,
        0, 0, 0, 0, 0, nullptr, nullptr);
    // V = relu(imb @ W_enc + b_enc), m-panel XCD swizzle
    gemm_k<0, true, true><<<dim3(NH / BN, (NB * NKK) / BM), 256, 0, stream>>>(
        imb, ND, Wenc_t, ND, b_enc, V_bf, NH, NH, ND, nullptr, nullptr, nullptr,
        1, 0, 0, 0, 0, nullptr, nullptr);
    // VA = V @ Wv + bv, m-panel XCD swizzle
    gemm_k<0, false, true><<<dim3(NH / BN, (NB * NKK) / BM), 256, 0, stream>>>(
        V_bf, NH, Wv_t, NH, bv, VA_bf, NH, NH, NH, nullptr, nullptr, nullptr,
        1, 0, 0, 0, 0, nullptr, nullptr);
    // Xpre = [emb|g] @ Wstep_top + bstep  (3840x5120, K=1024), n-chunked swizzle
    gemm_k<1, false, true><<<dim3(5120 / BN, (NT * NB) / BM), 256, 0, stream>>>(
        nullptr, 0, Wstep_t, 2048, bstep, Xpre, 5120, 5120, 1024, widx, embb, g_bf,
        4, 0, 0, 0, 0, nullptr, nullptr);

    // ---- recurrence: 30 steps ----
    for (int t = 0; t < NT; t++) {
        lstm_kernel<<<128, 256, 0, stream>>>(Xpre, ghh0, ghh1, ghh2, ghh3, c, H_all, S_all, t);
        if (t < NT - 1)
            gatesHH_kernel<<<320, 256, 0, stream>>>(
                H_all + (size_t)t * NB * NH, Wstep_t + 1024, ghh0, ghh1, ghh2, ghh3);
    }

    // ---- batched off-chain tail (all compact) ----
    // [HPa ; SWSa] = gather([H;S], live) @ [Wh ; Ws] + [bh ; bs]; n-chunked swz, early-exit
    gemm_k<2, false, true><<<dim3(NH / BN, NT, 2), 256, 0, stream>>>(
        H_all, NH, W2t, NH, b2, HPa, NH, NH, NH, nullptr, nullptr, nullptr,
        4, (size_t)NT * NB * NH, (size_t)NH * NH, (size_t)NH, (size_t)NT * NB * NH,
        live_tb, counts);
    attn_all_kernel<<<NT * NB, 256, 0, stream>>>(VA_bf, V_bf, HPa, SWSa, wa, H_all, S_all,
                                                 Z_all, live_tb, counts);

    if (useFull) {
        // logits: dense GEMM over compact Z; n-chunked swz + panel early-exit
        gemm_k<0, false, false><<<dim3(160, NT), 256, 0, stream>>>(
            Z_all, NH, Wout_t, NH, b_out, logitsF, NVOC, NVOC, NH, nullptr, nullptr, nullptr,
            4, 0, 0, 0, 0, nullptr, counts);
        softmax_kernel<true><<<NT * NB, 256, 0, stream>>>(logitsF, lens_s, row_of, pred, 0);
    } else {
        for (int c5 = 0; c5 < NT / CHT; c5++) {
            gemm_k<0, false, false><<<dim3(160, CHT), 256, 0, stream>>>(
                Z_all + (size_t)c5 * CHT * NB * NH, NH, Wout_t, NH, b_out, logitsC, NVOC,
                NVOC, NH, nullptr, nullptr, nullptr, 4, 0, 0, 0, 0, nullptr, nullptr);
            softmax_kernel<false><<<CHT * NB, 256, 0, stream>>>(logitsC, lens_s, nullptr, pred,
                                                                c5 * CHT);
        }
    }
}